// Round 1
// baseline (1262.893 us; speedup 1.0000x reference)
//
#include <hip/hip_runtime.h>
#include <hip/hip_fp16.h>
#include <math.h>

#define NATOM 8192  // NB * NLOC

namespace {

constexpr int KB_STRIDE = 132;   // kbuf row stride in halfs (128 + 4 pad)
constexpr int VB_STRIDE = 260;   // vbuf row stride in halfs (256 + 4 pad)

__device__ __forceinline__ float2 cvt2(unsigned u) {
  union { unsigned v; __half2 h; } x;
  x.v = u;
  return __half22float2(x.h);
}

__global__ __launch_bounds__(256, 2)
void local_atten_kernel(const float* __restrict__ g1,
                        const float* __restrict__ gg1,
                        const int* __restrict__ mask,
                        const float* __restrict__ Wq,
                        const float* __restrict__ Wkv,
                        const float* __restrict__ Wh,
                        const float* __restrict__ bh,
                        float* __restrict__ out) {
  // LDS: 8192 + 16896 + 33280 + 256 + 1024 + 1024 + 1024 + 1024 = 62720 B
  __shared__ __align__(16) __half gg1t[64][64];        // [i][j]  (transposed tile)
  __shared__ __align__(16) __half kbuf[64][KB_STRIDE]; // [j][(d&31)*4 + h]  transient per pass
  __shared__ __align__(16) __half vbuf[64][VB_STRIDE]; // [j][d*4 + h]       persistent
  __shared__ float g1s[64];
  __shared__ float qs[256];        // q flat col = d*4 + h
  __shared__ float aws[4][64];     // softmax weights [h][j]
  __shared__ float rets[256];      // o flat = h*64 + d
  __shared__ float redbuf[4][64];

  const int t = threadIdx.x;
  const int lane = t & 63;
  const int wave = t >> 6;
  const int atom = blockIdx.x;

  if (t < 64) g1s[t] = g1[(size_t)atom * 64 + t];

  // ---- stage gg1 tile (64 nei x 64 feat), transposed, fp16 ----
  {
    const float4* src = reinterpret_cast<const float4*>(gg1 + (size_t)atom * 4096);
#pragma unroll
    for (int r = 0; r < 4; ++r) {
      int idx4 = t + 256 * r;          // 0..1023 float4s
      int j = idx4 >> 4;               // neighbor row
      int i4 = (idx4 & 15) << 2;       // feature start
      float4 v = src[idx4];
      gg1t[i4 + 0][j] = __float2half(v.x);
      gg1t[i4 + 1][j] = __float2half(v.y);
      gg1t[i4 + 2][j] = __float2half(v.z);
      gg1t[i4 + 3][j] = __float2half(v.w);
    }
  }
  __syncthreads();

  // ---- q = g1row @ Wq : thread t owns flat column t (= d*4 + h) ----
  {
    float qacc = 0.f;
#pragma unroll 8
    for (int i = 0; i < 64; ++i) qacc = fmaf(g1s[i], Wq[i * 256 + t], qacc);
    qs[t] = qacc;
  }

  float score = 0.f;  // (h = wave, j = lane)

  // ---- kv GEMM in two d-halves; k consumed into partial scores per pass ----
#pragma unroll 1
  for (int p = 0; p < 2; ++p) {
    const int c = p * 256 + t;         // kv flat column = d*8 + ch
    const int d = c >> 3;
    const int ch = c & 7;

    float acc[64];
#pragma unroll
    for (int j = 0; j < 64; ++j) acc[j] = 0.f;

#pragma unroll 2
    for (int i = 0; i < 64; ++i) {
      const float w = Wkv[i * 512 + c];                       // coalesced, read once
      const uint4* gp = reinterpret_cast<const uint4*>(&gg1t[i][0]);
#pragma unroll
      for (int g = 0; g < 8; ++g) {
        uint4 u = gp[g];                                      // broadcast b128
        float2 f0 = cvt2(u.x), f1 = cvt2(u.y), f2 = cvt2(u.z), f3 = cvt2(u.w);
        const int j0 = g * 8;
        acc[j0 + 0] = fmaf(f0.x, w, acc[j0 + 0]);
        acc[j0 + 1] = fmaf(f0.y, w, acc[j0 + 1]);
        acc[j0 + 2] = fmaf(f1.x, w, acc[j0 + 2]);
        acc[j0 + 3] = fmaf(f1.y, w, acc[j0 + 3]);
        acc[j0 + 4] = fmaf(f2.x, w, acc[j0 + 4]);
        acc[j0 + 5] = fmaf(f2.y, w, acc[j0 + 5]);
        acc[j0 + 6] = fmaf(f3.x, w, acc[j0 + 6]);
        acc[j0 + 7] = fmaf(f3.y, w, acc[j0 + 7]);
      }
    }

    // store column: k goes to transient kbuf, v to persistent vbuf
    {
      __half* dst;
      int dstride;
      if (ch < 4) { dst = &kbuf[0][(d & 31) * 4 + ch]; dstride = KB_STRIDE; }
      else        { dst = &vbuf[0][d * 4 + (ch - 4)];  dstride = VB_STRIDE; }
#pragma unroll
      for (int j = 0; j < 64; ++j) dst[j * dstride] = __float2half(acc[j]);
    }
    __syncthreads();

    // partial scores for d in [p*32, p*32+32): h = wave, j = lane
    {
      float sc = 0.f;
#pragma unroll 8
      for (int dd = 0; dd < 32; ++dd) {
        float qv = qs[(p * 32 + dd) * 4 + wave];              // broadcast
        float kv = __half2float(kbuf[lane][dd * 4 + wave]);
        sc = fmaf(qv, kv, sc);
      }
      score += sc;
    }
    __syncthreads();  // kbuf reused by next pass
  }

  // ---- masked softmax over j (wave-wide, 64 lanes) ----
  {
    score *= 0.125f;                                          // 1/sqrt(64)
    const int m = mask[(size_t)atom * 64 + lane];
    float s = m ? score : -INFINITY;
    float mx = s;
#pragma unroll
    for (int off = 32; off > 0; off >>= 1) mx = fmaxf(mx, __shfl_xor(mx, off));
    float pe = m ? __expf(s - mx) : 0.f;
    float sum = pe;
#pragma unroll
    for (int off = 32; off > 0; off >>= 1) sum += __shfl_xor(sum, off);
    float aw = (sum > 0.f) ? (pe / sum) : 0.f;
    aws[wave][lane] = aw;
  }
  __syncthreads();

  // ---- o[h][d] = sum_j aw[h][j] * v[h][j][d] : h = wave, d = lane ----
  {
    float o = 0.f;
#pragma unroll 8
    for (int j = 0; j < 64; ++j) {
      float a = aws[wave][j];                                 // broadcast
      float vv = __half2float(vbuf[j][lane * 4 + wave]);
      o = fmaf(a, vv, o);
    }
    rets[wave * 64 + lane] = o;
  }
  __syncthreads();

  // ---- out = ret @ Wh + bh : 4 partial sums then tree-add ----
  {
    float part = 0.f;
#pragma unroll 8
    for (int k = 0; k < 64; ++k)
      part = fmaf(rets[wave * 64 + k], Wh[(wave * 64 + k) * 64 + lane], part);
    redbuf[wave][lane] = part;
  }
  __syncthreads();
  if (t < 64)
    out[(size_t)atom * 64 + t] =
        redbuf[0][t] + redbuf[1][t] + redbuf[2][t] + redbuf[3][t] + bh[t];
}

}  // namespace

extern "C" void kernel_launch(void* const* d_in, const int* in_sizes, int n_in,
                              void* d_out, int out_size, void* d_ws, size_t ws_size,
                              hipStream_t stream) {
  const float* g1   = (const float*)d_in[0];
  const float* gg1  = (const float*)d_in[1];
  const int*   mask = (const int*)d_in[2];
  const float* Wq   = (const float*)d_in[3];
  const float* Wkv  = (const float*)d_in[4];
  const float* Wh   = (const float*)d_in[5];
  const float* bh   = (const float*)d_in[6];
  float* out = (float*)d_out;
  (void)in_sizes; (void)n_in; (void)d_ws; (void)ws_size; (void)out_size;

  local_atten_kernel<<<NATOM, 256, 0, stream>>>(g1, gg1, mask, Wq, Wkv, Wh, bh, out);
}

// Round 2
// 311.184 us; speedup vs baseline: 4.0583x; 4.0583x over previous
//
#include <hip/hip_runtime.h>
#include <hip/hip_fp16.h>
#include <math.h>

#define NATOM 8192  // NB * NLOC

namespace {

typedef _Float16 half8 __attribute__((ext_vector_type(8)));
typedef float f32x4 __attribute__((ext_vector_type(4)));

constexpr int KB_STRIDE = 132;   // kbuf row stride in halfs (128 + 4 pad)
constexpr int VB_STRIDE = 260;   // vbuf row stride in halfs (256 + 4 pad)

// Pack Wkv (64x512 fp32, row-major) into fp16 A-fragment order for
// mfma_f32_16x16x32_f16 computing C^T = Wkv^T @ gg1^T:
//   out[((ct*2+ks)*64 + l)*8 + jj] = Wkv[(ks*32 + (l>>4)*8 + jj)*512 + ct*16 + (l&15)]
// (ct = 16-col tile of the kv flat column dim, ks = k-step, l = lane)
__global__ void pack_wkv(const float* __restrict__ Wkv, _Float16* __restrict__ out) {
  int tid = blockIdx.x * 256 + threadIdx.x;  // 0..32767
  int jj = tid & 7;
  int l  = (tid >> 3) & 63;
  int ks = (tid >> 9) & 1;
  int ct = tid >> 10;
  int i  = ks * 32 + ((l >> 4) << 3) + jj;
  int c  = ct * 16 + (l & 15);
  out[tid] = (_Float16)Wkv[i * 512 + c];
}

__global__ __launch_bounds__(256, 2)
void local_atten_kernel(const float* __restrict__ g1,
                        const float* __restrict__ gg1,
                        const int* __restrict__ mask,
                        const float* __restrict__ Wq,
                        const _Float16* __restrict__ wkvp,
                        const float* __restrict__ Wh,
                        const float* __restrict__ bh,
                        float* __restrict__ out) {
  // LDS: 8192 + 16896 + 33280 + 256 + 1024 + 1024 + 1024 + 1024 = 62720 B
  __shared__ __align__(16) __half gs[64 * 64];          // gg1 tile, XOR-swizzled
  __shared__ __align__(16) __half kbuf[64][KB_STRIDE];  // [j][(d&31)*4 + h] transient/pass
  __shared__ __align__(16) __half vbuf[64][VB_STRIDE];  // [j][d*4 + h]      persistent
  __shared__ float g1s[64];
  __shared__ float qs[256];        // q flat col = d*4 + h
  __shared__ float aws[4][64];     // softmax weights [h][j]
  __shared__ float rets[256];      // o flat = h*64 + d
  __shared__ float redbuf[4][64];

  const int t = threadIdx.x;
  const int lane = t & 63;
  const int wave = t >> 6;
  const int lq = lane >> 4;   // quad within wave
  const int lr = lane & 15;
  const int atom = blockIdx.x;

  if (t < 64) g1s[t] = g1[(size_t)atom * 64 + t];

  // ---- stage gg1 tile (64 nei x 64 feat) as fp16, swizzled for B-frag b128 ----
  // logical gs[j][i]; physical half offset = j*64 + ((g ^ (j&7))<<3) + (i&7), g=i>>3
  {
    const float4* src = reinterpret_cast<const float4*>(gg1 + (size_t)atom * 4096);
#pragma unroll
    for (int r = 0; r < 4; ++r) {
      int idx4 = t + 256 * r;          // 0..1023 float4s
      int j = idx4 >> 4;               // neighbor row
      int i4 = (idx4 & 15) << 2;       // feature start (multiple of 4)
      float4 v = src[idx4];
      __half2 h01 = __floats2half2_rn(v.x, v.y);
      __half2 h23 = __floats2half2_rn(v.z, v.w);
      int g = i4 >> 3;
      int addr = j * 64 + ((g ^ (j & 7)) << 3) + (i4 & 7);
      union { __half2 h[2]; uint2 u; } pk;
      pk.h[0] = h01; pk.h[1] = h23;
      *reinterpret_cast<uint2*>(&gs[addr]) = pk.u;
    }
  }
  __syncthreads();

  // ---- q = g1row @ Wq : thread t owns flat column t (= d*4 + h) ----
  {
    float qacc = 0.f;
#pragma unroll 8
    for (int i = 0; i < 64; ++i) qacc = fmaf(g1s[i], Wq[i * 256 + t], qacc);
    qs[t] = qacc;
  }

  // ---- B-fragments (gg1) for all 4 j-tiles x 2 k-steps, kept in regs ----
  half8 bfrag[4][2];
#pragma unroll
  for (int jt = 0; jt < 4; ++jt) {
#pragma unroll
    for (int ks = 0; ks < 2; ++ks) {
      int j = jt * 16 + lr;
      int g = ks * 4 + lq;
      bfrag[jt][ks] =
          *reinterpret_cast<const half8*>(&gs[j * 64 + ((g ^ (j & 7)) << 3)]);
    }
  }

  float score = 0.f;  // (h = wave, j = lane)

  // ---- kv GEMM via MFMA, two passes over d-halves (c in [p*256, p*256+256)) ----
#pragma unroll 1
  for (int p = 0; p < 2; ++p) {
#pragma unroll
    for (int ct8 = 0; ct8 < 4; ++ct8) {
      int ct = p * 16 + wave * 4 + ct8;      // global 16-col tile index (0..31)
      const half8* ap = reinterpret_cast<const half8*>(wkvp) + ct * 128;
      half8 a0 = ap[lane];        // ks=0
      half8 a1 = ap[64 + lane];   // ks=1
#pragma unroll
      for (int jt = 0; jt < 4; ++jt) {
        f32x4 acc = {0.f, 0.f, 0.f, 0.f};
        acc = __builtin_amdgcn_mfma_f32_16x16x32_f16(a0, bfrag[jt][0], acc, 0, 0, 0);
        acc = __builtin_amdgcn_mfma_f32_16x16x32_f16(a1, bfrag[jt][1], acc, 0, 0, 0);
        // lane holds C'[c = ct*16 + lq*4 + r][j = jt*16 + lr], r=0..3
        int c0 = ct * 16 + lq * 4;
        int j  = jt * 16 + lr;
        int d  = c0 >> 3;                    // global d (0..63)
        __half2 h01 = __floats2half2_rn(acc[0], acc[1]);
        __half2 h23 = __floats2half2_rn(acc[2], acc[3]);
        union { __half2 h[2]; uint2 u; } pk;
        pk.h[0] = h01; pk.h[1] = h23;
        // (c0&7) is 0 for even quads (k-channels 0..3) and 4 for odd (v-channels)
        __half* dst = (lq & 1) ? &vbuf[j][d * 4] : &kbuf[j][(d & 31) * 4];
        *reinterpret_cast<uint2*>(dst) = pk.u;
      }
    }
    __syncthreads();

    // partial scores for d in [p*32, p*32+32): h = wave, j = lane
    {
      float sc = 0.f;
#pragma unroll 8
      for (int dd = 0; dd < 32; ++dd) {
        float qv = qs[(p * 32 + dd) * 4 + wave];              // broadcast
        float kv = __half2float(kbuf[lane][dd * 4 + wave]);
        sc = fmaf(qv, kv, sc);
      }
      score += sc;
    }
    __syncthreads();  // kbuf reused by next pass
  }

  // ---- masked softmax over j (wave-wide, 64 lanes) ----
  {
    score *= 0.125f;                                          // 1/sqrt(64)
    const int m = mask[(size_t)atom * 64 + lane];
    float s = m ? score : -INFINITY;
    float mx = s;
#pragma unroll
    for (int off = 32; off > 0; off >>= 1) mx = fmaxf(mx, __shfl_xor(mx, off));
    float pe = m ? __expf(s - mx) : 0.f;
    float sum = pe;
#pragma unroll
    for (int off = 32; off > 0; off >>= 1) sum += __shfl_xor(sum, off);
    float aw = (sum > 0.f) ? (pe / sum) : 0.f;
    aws[wave][lane] = aw;
  }
  __syncthreads();

  // ---- o[h][d] = sum_j aw[h][j] * v[h][j][d] : h = wave, d = lane ----
  {
    float o = 0.f;
#pragma unroll 8
    for (int j = 0; j < 64; ++j) {
      float a = aws[wave][j];                                 // broadcast
      float vv = __half2float(vbuf[j][lane * 4 + wave]);
      o = fmaf(a, vv, o);
    }
    rets[wave * 64 + lane] = o;
  }
  __syncthreads();

  // ---- out = ret @ Wh + bh : 4 partial sums then tree-add ----
  {
    float part = 0.f;
#pragma unroll 8
    for (int k = 0; k < 64; ++k)
      part = fmaf(rets[wave * 64 + k], Wh[(wave * 64 + k) * 64 + lane], part);
    redbuf[wave][lane] = part;
  }
  __syncthreads();
  if (t < 64)
    out[(size_t)atom * 64 + t] =
        redbuf[0][t] + redbuf[1][t] + redbuf[2][t] + redbuf[3][t] + bh[t];
}

}  // namespace

extern "C" void kernel_launch(void* const* d_in, const int* in_sizes, int n_in,
                              void* d_out, int out_size, void* d_ws, size_t ws_size,
                              hipStream_t stream) {
  const float* g1   = (const float*)d_in[0];
  const float* gg1  = (const float*)d_in[1];
  const int*   mask = (const int*)d_in[2];
  const float* Wq   = (const float*)d_in[3];
  const float* Wkv  = (const float*)d_in[4];
  const float* Wh   = (const float*)d_in[5];
  const float* bh   = (const float*)d_in[6];
  float* out = (float*)d_out;
  (void)in_sizes; (void)n_in; (void)ws_size; (void)out_size;

  _Float16* wkvp = (_Float16*)d_ws;   // 32768 halfs = 64 KB
  pack_wkv<<<128, 256, 0, stream>>>(Wkv, wkvp);
  local_atten_kernel<<<NATOM, 256, 0, stream>>>(g1, gg1, mask, Wq, wkvp, Wh, bh, out);
}

// Round 3
// 276.432 us; speedup vs baseline: 4.5686x; 1.1257x over previous
//
#include <hip/hip_runtime.h>
#include <hip/hip_fp16.h>
#include <math.h>

#define NATOM 8192  // NB * NLOC

namespace {

typedef _Float16 half8 __attribute__((ext_vector_type(8)));
typedef float f32x4 __attribute__((ext_vector_type(4)));

constexpr int VB_STRIDE = 260;   // vbuf row stride in halfs (256 + 4 pad)

// Pack Wkv (64x512 fp32, row-major) into fp16 A-fragment order for
// mfma_f32_16x16x32_f16 computing C^T = Wkv^T @ gg1^T:
//   out[((ct*2+ks)*64 + l)*8 + jj] = Wkv[(ks*32 + (l>>4)*8 + jj)*512 + ct*16 + (l&15)]
__global__ void pack_wkv(const float* __restrict__ Wkv, _Float16* __restrict__ out) {
  int tid = blockIdx.x * 256 + threadIdx.x;  // 0..32767
  int jj = tid & 7;
  int l  = (tid >> 3) & 63;
  int ks = (tid >> 9) & 1;
  int ct = tid >> 10;
  int i  = ks * 32 + ((l >> 4) << 3) + jj;
  int c  = ct * 16 + (l & 15);
  out[tid] = (_Float16)Wkv[i * 512 + c];
}

__global__ __launch_bounds__(256, 4)
void local_atten_kernel(const float* __restrict__ g1,
                        const float* __restrict__ gg1,
                        const int* __restrict__ mask,
                        const float* __restrict__ Wq,
                        const _Float16* __restrict__ wkvp,
                        const float* __restrict__ Wh,
                        const float* __restrict__ bh,
                        float* __restrict__ out) {
  // LDS: 33280 + 256 + 1024 + 2048 + 1024 + 512 + 1024 = 39168 B -> 4 blocks/CU
  __shared__ __align__(16) __half vraw[64 * VB_STRIDE]; // vbuf; first 8 KB aliased as gs
  __shared__ float g1s[64];
  __shared__ __align__(16) float qs[256];   // q flat col = d*4 + h
  __shared__ __half sred[4][4][64];         // score partials [wave][h][j]
  __shared__ float aws[4][64];              // softmax weights [h][j]
  __shared__ __half rets[256];              // o flat = h*64 + d
  __shared__ float redbuf[4][64];

  const int t = threadIdx.x;
  const int lane = t & 63;
  const int wave = t >> 6;
  const int lq = lane >> 4;   // quad within wave
  const int lr = lane & 15;
  const int atom = blockIdx.x;

  __half* gs = vraw;                                      // alias (staging phase only)
  auto vbuf = reinterpret_cast<__half(*)[VB_STRIDE]>(vraw);

  if (t < 64) g1s[t] = g1[(size_t)atom * 64 + t];

  // ---- stage gg1 tile (64 nei x 64 feat) as fp16, swizzled for B-frag b128 ----
  // logical gs[j][i]; physical half offset = j*64 + ((g ^ (j&7))<<3) + (i&7), g=i>>3
  {
    const float4* src = reinterpret_cast<const float4*>(gg1 + (size_t)atom * 4096);
#pragma unroll
    for (int r = 0; r < 4; ++r) {
      int idx4 = t + 256 * r;          // 0..1023 float4s
      int j = idx4 >> 4;               // neighbor row
      int i4 = (idx4 & 15) << 2;       // feature start (multiple of 4)
      float4 v = src[idx4];
      __half2 h01 = __floats2half2_rn(v.x, v.y);
      __half2 h23 = __floats2half2_rn(v.z, v.w);
      int g = i4 >> 3;
      int addr = j * 64 + ((g ^ (j & 7)) << 3) + (i4 & 7);
      union { __half2 h[2]; uint2 u; } pk;
      pk.h[0] = h01; pk.h[1] = h23;
      *reinterpret_cast<uint2*>(&gs[addr]) = pk.u;
    }
  }
  __syncthreads();

  // ---- B-fragments (gg1) for all 4 j-tiles x 2 k-steps, kept in regs ----
  half8 bfrag[4][2];
#pragma unroll
  for (int jt = 0; jt < 4; ++jt) {
#pragma unroll
    for (int ks = 0; ks < 2; ++ks) {
      int j = jt * 16 + lr;
      int g = ks * 4 + lq;
      bfrag[jt][ks] =
          *reinterpret_cast<const half8*>(&gs[j * 64 + ((g ^ (j & 7)) << 3)]);
    }
  }

  // ---- q = g1row @ Wq : thread t owns flat column t (= d*4 + h) ----
  {
    float qacc = 0.f;
#pragma unroll 8
    for (int i = 0; i < 64; ++i) qacc = fmaf(g1s[i], Wq[i * 256 + t], qacc);
    qs[t] = qacc;
  }
  __syncthreads();   // bfrags read (gs dead), qs ready -> vbuf may overwrite gs

  // ---- kv GEMM via MFMA; k consumed into register score partials, v -> LDS ----
  // Lane holds C'[c = ct*16 + lq*4 + r][j = jt*16 + lr]; even quads: k (head=r),
  // odd quads: v (head=r); d = ct*2 + (lq>>1).
  float sacc[4][4];  // [jt][h], meaningful on even-quad lanes
#pragma unroll
  for (int jt = 0; jt < 4; ++jt)
#pragma unroll
    for (int h = 0; h < 4; ++h) sacc[jt][h] = 0.f;

  const bool isv = (lq & 1);
#pragma unroll 2
  for (int it = 0; it < 8; ++it) {
    const int ct = ((it >> 2) << 4) + wave * 4 + (it & 3);  // 16-col tile (0..31)
    const half8* ap = reinterpret_cast<const half8*>(wkvp) + ct * 128;
    half8 a0 = ap[lane];        // ks=0
    half8 a1 = ap[64 + lane];   // ks=1
    const int d = ct * 2 + (lq >> 1);

    f32x4 accs[4];
#pragma unroll
    for (int jt = 0; jt < 4; ++jt) {
      f32x4 acc = {0.f, 0.f, 0.f, 0.f};
      acc = __builtin_amdgcn_mfma_f32_16x16x32_f16(a0, bfrag[jt][0], acc, 0, 0, 0);
      acc = __builtin_amdgcn_mfma_f32_16x16x32_f16(a1, bfrag[jt][1], acc, 0, 0, 0);
      accs[jt] = acc;
    }

    if (isv) {
#pragma unroll
      for (int jt = 0; jt < 4; ++jt) {
        int j = jt * 16 + lr;
        __half2 h01 = __floats2half2_rn(accs[jt][0], accs[jt][1]);
        __half2 h23 = __floats2half2_rn(accs[jt][2], accs[jt][3]);
        union { __half2 h[2]; uint2 u; } pk;
        pk.h[0] = h01; pk.h[1] = h23;
        *reinterpret_cast<uint2*>(&vbuf[j][d * 4]) = pk.u;
      }
    } else {
      float4 q4 = *reinterpret_cast<const float4*>(&qs[d * 4]);  // broadcast b128
#pragma unroll
      for (int jt = 0; jt < 4; ++jt) {
        sacc[jt][0] = fmaf(accs[jt][0], q4.x, sacc[jt][0]);
        sacc[jt][1] = fmaf(accs[jt][1], q4.y, sacc[jt][1]);
        sacc[jt][2] = fmaf(accs[jt][2], q4.z, sacc[jt][2]);
        sacc[jt][3] = fmaf(accs[jt][3], q4.w, sacc[jt][3]);
      }
    }
  }

  // fold even quads (lq=0 <- lq=2, lane XOR 32) and publish score partials
#pragma unroll
  for (int jt = 0; jt < 4; ++jt)
#pragma unroll
    for (int h = 0; h < 4; ++h)
      sacc[jt][h] += __shfl_xor(sacc[jt][h], 32);
  if (lq == 0) {
#pragma unroll
    for (int h = 0; h < 4; ++h)
#pragma unroll
      for (int jt = 0; jt < 4; ++jt)
        sred[wave][h][jt * 16 + lr] = __float2half(sacc[jt][h]);
  }
  __syncthreads();

  // ---- masked softmax over j (wave-wide): h = wave, j = lane ----
  {
    float s = __half2float(sred[0][wave][lane]) + __half2float(sred[1][wave][lane]) +
              __half2float(sred[2][wave][lane]) + __half2float(sred[3][wave][lane]);
    s *= 0.125f;                                          // 1/sqrt(64)
    const int m = mask[(size_t)atom * 64 + lane];
    s = m ? s : -INFINITY;
    float mx = s;
#pragma unroll
    for (int off = 32; off > 0; off >>= 1) mx = fmaxf(mx, __shfl_xor(mx, off));
    float pe = m ? __expf(s - mx) : 0.f;
    float sum = pe;
#pragma unroll
    for (int off = 32; off > 0; off >>= 1) sum += __shfl_xor(sum, off);
    aws[wave][lane] = (sum > 0.f) ? (pe / sum) : 0.f;
  }
  __syncthreads();

  // ---- o[h][d] = sum_j aw[h][j] * v[h][j][d] : h = wave, d = lane ----
  {
    float o = 0.f;
#pragma unroll 8
    for (int j = 0; j < 64; ++j) {
      float a = aws[wave][j];                               // broadcast
      float vv = __half2float(vbuf[j][lane * 4 + wave]);
      o = fmaf(a, vv, o);
    }
    rets[wave * 64 + lane] = __float2half(o);
  }
  __syncthreads();

  // ---- out = ret @ Wh + bh : 4 partial sums then tree-add ----
  {
    float part = 0.f;
#pragma unroll 8
    for (int k = 0; k < 64; ++k)
      part = fmaf(__half2float(rets[wave * 64 + k]), Wh[(wave * 64 + k) * 64 + lane],
                  part);
    redbuf[wave][lane] = part;
  }
  __syncthreads();
  if (t < 64)
    out[(size_t)atom * 64 + t] =
        redbuf[0][t] + redbuf[1][t] + redbuf[2][t] + redbuf[3][t] + bh[t];
}

}  // namespace

extern "C" void kernel_launch(void* const* d_in, const int* in_sizes, int n_in,
                              void* d_out, int out_size, void* d_ws, size_t ws_size,
                              hipStream_t stream) {
  const float* g1   = (const float*)d_in[0];
  const float* gg1  = (const float*)d_in[1];
  const int*   mask = (const int*)d_in[2];
  const float* Wq   = (const float*)d_in[3];
  const float* Wkv  = (const float*)d_in[4];
  const float* Wh   = (const float*)d_in[5];
  const float* bh   = (const float*)d_in[6];
  float* out = (float*)d_out;
  (void)in_sizes; (void)n_in; (void)ws_size; (void)out_size;

  _Float16* wkvp = (_Float16*)d_ws;   // 32768 halfs = 64 KB
  pack_wkv<<<128, 256, 0, stream>>>(Wkv, wkvp);
  local_atten_kernel<<<NATOM, 256, 0, stream>>>(g1, gg1, mask, Wq, wkvp, Wh, bh, out);
}